// Round 5
// baseline (1643.007 us; speedup 1.0000x reference)
//
#include <hip/hip_runtime.h>
#include <hip/hip_cooperative_groups.h>
#include <hip/hip_bf16.h>
#include <hip/hip_fp16.h>
#include <stdint.h>

#define DIM 256
#define NG 8192
#define KDIM 512      // 2*DIM (concat [readout | h])
#define GDIM 1024     // 4*DIM gates
#define N_ITERS 6

#define BM 128
#define BN 128
#define BK 64
#define GRID_BLOCKS 512   // == (NG/BM) * (GDIM/BN) tile grid; 2 blocks/CU co-resident

namespace cg = cooperative_groups;

typedef __hip_bfloat16 bf16;
typedef __attribute__((ext_vector_type(8))) short bf16x8;
typedef __attribute__((ext_vector_type(4))) float f32x4;
typedef __attribute__((ext_vector_type(8))) unsigned short u16x8;
typedef __attribute__((ext_vector_type(4))) unsigned short u16x4;

struct Pm {
    const float* xf; const int* batch;
    const float* Wih; const float* Whh; const float* bih; const float* bhh;
    int n_nodes;
    float* out;
    int* offs; bf16* Wcat; float* bsum;
    bf16* Acat0; bf16* Acat1;
    float* h; float* c;
    unsigned short* xb;
};

struct SMU {
    union {
        struct { bf16 As[BM * BK]; bf16 Bs[BN * BK]; } st;  // 32 KB staging
        float ep[32][132];                                   // epilogue transpose
    };
};

// ---------------- helpers --------------
__device__ __forceinline__ void async16(void* lds, const void* g) {
    __builtin_amdgcn_global_load_lds((const __attribute__((address_space(1))) void*)g,
                                     (__attribute__((address_space(3))) void*)lds, 16, 0, 0);
}
__device__ __forceinline__ float fast_sigmoid(float v) {
    return 1.0f / (1.0f + __expf(-v));
}
__device__ __forceinline__ float fast_tanh(float v) {
    float e = __expf(2.0f * v);
    return (e - 1.0f) / (e + 1.0f);
}
__device__ __forceinline__ unsigned short f2bf(float v) {
    __hip_bfloat16 t = __float2bfloat16(v);
    unsigned short u; __builtin_memcpy(&u, &t, 2); return u;
}
__device__ __forceinline__ unsigned short f2h(float v) {
    __half t = __float2half_rn(v);
    unsigned short u; __builtin_memcpy(&u, &t, 2); return u;
}
__device__ __forceinline__ float h2f(unsigned short u) {
    __half t; __builtin_memcpy(&t, &u, 2);
    return __half2float(t);
}

// ---------------- prep: CSR offsets + W interleave/cast + zero-init (grid-stride) ------
__device__ __forceinline__ void do_prep(const Pm& p) {
    const int tid = blockIdx.x * 256 + threadIdx.x;
    const int NT = gridDim.x * 256;
    for (int i = tid; i < NG * DIM; i += NT) {
        p.h[i] = 0.0f; p.c[i] = 0.0f;
        p.Acat0[(size_t)(i >> 8) * KDIM + DIM + (i & 255)] = __float2bfloat16(0.0f);
    }
    for (int i = tid; i < GDIM * KDIM; i += NT) {
        const int n = i >> 9, k = i & (KDIM - 1);
        const int d = n >> 2, gate = n & 3;
        const int j = gate * DIM + d;
        const float v = (k < DIM) ? p.Wih[j * DIM + k] : p.Whh[j * DIM + k - DIM];
        p.Wcat[i] = __float2bfloat16(v);
    }
    if (tid < GDIM) {
        const int d = tid >> 2, gate = tid & 3;
        p.bsum[tid] = p.bih[gate * DIM + d] + p.bhh[gate * DIM + d];
    }
    for (int i = tid; i < p.n_nodes; i += NT) {
        const int b = p.batch[i];
        const int bp = (i == 0) ? -1 : p.batch[i - 1];
        for (int g2 = bp + 1; g2 <= b; ++g2) p.offs[g2] = i;
        if (i == p.n_nodes - 1)
            for (int g2 = b + 1; g2 <= NG; ++g2) p.offs[g2] = p.n_nodes;
    }
}

// ---------------- attention: one wave per graph, register online-softmax --------------
template <bool FIRST>
__device__ __forceinline__ void load_row(const Pm& p, int r, int hl, float xv[8]) {
    if (FIRST) {
        const float4 a = *(const float4*)&p.xf[(size_t)r * DIM + hl * 8];
        const float4 b = *(const float4*)&p.xf[(size_t)r * DIM + hl * 8 + 4];
        xv[0] = a.x; xv[1] = a.y; xv[2] = a.z; xv[3] = a.w;
        xv[4] = b.x; xv[5] = b.y; xv[6] = b.z; xv[7] = b.w;
        u16x8 pk;
        #pragma unroll
        for (int j = 0; j < 8; ++j) pk[j] = f2h(xv[j]);
        *(u16x8*)&p.xb[(size_t)r * DIM + hl * 8] = pk;
    } else {
        const u16x8 pk = *(const u16x8*)&p.xb[(size_t)r * DIM + hl * 8];
        #pragma unroll
        for (int j = 0; j < 8; ++j) xv[j] = h2f(pk[j]);
    }
}

template <bool FIRST, bool LAST>
__device__ __forceinline__ void att_phase(const Pm& p, bf16* AcatOut) {
    const int wave = threadIdx.x >> 6, lane = threadIdx.x & 63;
    const int half = lane >> 5, hl = lane & 31;
    const int wg = blockIdx.x * 4 + wave;          // 0..2047; 4 graphs each

    for (int gi = 0; gi < 4; ++gi) {
        const int g = wg * 4 + gi;
        float hreg[8];
        {
            const float4 a = *(const float4*)&p.h[(size_t)g * DIM + hl * 8];
            const float4 b = *(const float4*)&p.h[(size_t)g * DIM + hl * 8 + 4];
            hreg[0] = a.x; hreg[1] = a.y; hreg[2] = a.z; hreg[3] = a.w;
            hreg[4] = b.x; hreg[5] = b.y; hreg[6] = b.z; hreg[7] = b.w;
        }
        const int start = p.offs[g], end = p.offs[g + 1];
        float racc[8] = {0, 0, 0, 0, 0, 0, 0, 0};
        float m = 0.0f;   // running max; init 0 == max(seg_max, 0) clamp
        float s = 0.0f;

        float xv[8];      // 1-deep prefetch to break the load->use chain
        {
            const int r = start + half;
            if (r < end) load_row<FIRST>(p, r, hl, xv);
        }
        for (int r0 = start; r0 < end; r0 += 2) {
            const int r = r0 + half;
            const bool valid = (r < end);
            float cur[8];
            #pragma unroll
            for (int j = 0; j < 8; ++j) cur[j] = xv[j];
            const int rn = r0 + 2 + half;
            if (rn < end) load_row<FIRST>(p, rn, hl, xv);   // issue next load early
            float dt = 0.0f;
            if (valid) {
                #pragma unroll
                for (int j = 0; j < 8; ++j) dt = fmaf(cur[j], hreg[j], dt);
            }
            #pragma unroll
            for (int off = 16; off > 0; off >>= 1) dt += __shfl_xor(dt, off);
            if (valid) {
                const float mn = fmaxf(m, dt);
                const float al = __expf(m - mn);
                const float e  = __expf(dt - mn);
                s = s * al + e;
                #pragma unroll
                for (int j = 0; j < 8; ++j) racc[j] = fmaf(racc[j], al, e * cur[j]);
                m = mn;
            }
        }

        // merge the two halves (online-softmax merge)
        const float mo = __shfl_xor(m, 32);
        const float M  = fmaxf(m, mo);
        const float al = __expf(m - M);
        s *= al;
        #pragma unroll
        for (int j = 0; j < 8; ++j) racc[j] *= al;
        s += __shfl_xor(s, 32);
        #pragma unroll
        for (int j = 0; j < 8; ++j) racc[j] += __shfl_xor(racc[j], 32);
        const float inv = 1.0f / (s + 1e-8f);
        float o[8];
        #pragma unroll
        for (int j = 0; j < 8; ++j) o[j] = racc[j] * inv;

        if (half == 0) {            // bf16 readout-half of A for the GEMM
            u16x8 pk;
            #pragma unroll
            for (int j = 0; j < 8; ++j) pk[j] = f2bf(o[j]);
            *(u16x8*)&AcatOut[(size_t)g * KDIM + hl * 8] = pk;
        } else if (LAST) {          // fp32 readout straight into out[:, 256:512]
            float* rout = p.out + DIM;
            *(float4*)&rout[(size_t)g * KDIM + hl * 8]     = make_float4(o[0], o[1], o[2], o[3]);
            *(float4*)&rout[(size_t)g * KDIM + hl * 8 + 4] = make_float4(o[4], o[5], o[6], o[7]);
        }
    }
}

// ---------------- GEMM + fused LSTM cell: one 128x128 tile per block -------------------
template <bool LAST>
__device__ __forceinline__ void gemm_phase(const Pm& p, SMU& sm, const bf16* A, bf16* AcatN) {
    const int tid = threadIdx.x;
    const int wave = tid >> 6, lane = tid & 63;
    const int m0 = (blockIdx.x >> 3) * BM;
    const int n0 = (blockIdx.x & 7) * BN;
    const int wr = wave >> 1, wc = wave & 1;
    const bf16* W = p.Wcat;

    f32x4 acc[4][4] = {};
    const int chunk = lane & 7;

    for (int k0 = 0; k0 < KDIM; k0 += BK) {
        #pragma unroll
        for (int i = 0; i < 4; ++i) {
            const int grp = wave * 32 + i * 8;
            async16(&sm.st.As[grp * BK],
                    A + (size_t)(m0 + grp + (lane >> 3)) * KDIM + k0 + chunk * 8);
        }
        #pragma unroll
        for (int i = 0; i < 4; ++i) {
            const int grp = wave * 32 + i * 8;
            async16(&sm.st.Bs[grp * BK],
                    W + (size_t)(n0 + grp + (lane >> 3)) * KDIM + k0 + chunk * 8);
        }
        asm volatile("s_waitcnt vmcnt(0)" ::: "memory");
        __syncthreads();

        #pragma unroll
        for (int ks = 0; ks < BK; ks += 32) {
            bf16x8 a[4], b[4];
            #pragma unroll
            for (int mi = 0; mi < 4; ++mi)
                a[mi] = *(const bf16x8*)&sm.st.As[(wr * 64 + mi * 16 + (lane & 15)) * BK + ks + (lane >> 4) * 8];
            #pragma unroll
            for (int ni = 0; ni < 4; ++ni)
                b[ni] = *(const bf16x8*)&sm.st.Bs[(wc * 64 + ni * 16 + (lane & 15)) * BK + ks + (lane >> 4) * 8];
            #pragma unroll
            for (int mi = 0; mi < 4; ++mi)
                #pragma unroll
                for (int ni = 0; ni < 4; ++ni)
                    acc[mi][ni] = __builtin_amdgcn_mfma_f32_16x16x32_bf16(a[mi], b[ni], acc[mi][ni], 0, 0, 0);
        }
        __syncthreads();
    }

    // ---- fused LSTM-cell epilogue ----
    float bv[4];
    #pragma unroll
    for (int ni = 0; ni < 4; ++ni)
        bv[ni] = p.bsum[n0 + wc * 64 + ni * 16 + (lane & 15)];

    const int d0 = n0 >> 2;            // 32 d-values per block
    const int lr = tid >> 3;           // local row 0..31
    const int dd = (tid & 7) * 4;      // 4 consecutive d per thread

    #pragma unroll
    for (int mi = 0; mi < 4; ++mi) {
        __syncthreads();
        #pragma unroll
        for (int ni = 0; ni < 4; ++ni) {
            const int colL = wc * 64 + ni * 16 + (lane & 15);
            #pragma unroll
            for (int r = 0; r < 4; ++r) {
                const int lrow = wr * 16 + (lane >> 4) * 4 + r;
                sm.ep[lrow][colL] = acc[mi][ni][r] + bv[ni];
            }
        }
        __syncthreads();
        const int grow = m0 + (lr >> 4) * 64 + mi * 16 + (lr & 15);
        const int d = d0 + dd;
        float co[4], cn[4], hn[4];
        *(float4*)co = *(const float4*)&p.c[(size_t)grow * DIM + d];
        u16x4 hb;
        #pragma unroll
        for (int j = 0; j < 4; ++j) {
            const float4 q = *(const float4*)&sm.ep[lr][(dd + j) * 4]; // i,f,g,o
            cn[j] = fast_sigmoid(q.y) * co[j] + fast_sigmoid(q.x) * fast_tanh(q.z);
            hn[j] = fast_sigmoid(q.w) * fast_tanh(cn[j]);
            hb[j] = f2bf(hn[j]);
        }
        if (LAST) {
            *(float4*)&p.out[(size_t)grow * KDIM + d] = *(float4*)hn;   // out[:,0:256]
        } else {
            *(float4*)&p.c[(size_t)grow * DIM + d] = *(float4*)cn;
            *(float4*)&p.h[(size_t)grow * DIM + d] = *(float4*)hn;
            *(u16x4*)&AcatN[(size_t)grow * KDIM + DIM + d] = hb;
        }
    }
}

// ---------------- the single cooperative kernel ----------------
__global__ __launch_bounds__(256, 2) void k_fused(Pm p) {
    cg::grid_group grid = cg::this_grid();
    __shared__ SMU sm;

    do_prep(p);
    grid.sync();

    for (int it = 0; it < N_ITERS; ++it) {
        bf16* Ain  = (it & 1) ? p.Acat1 : p.Acat0;
        bf16* Aout = (it & 1) ? p.Acat0 : p.Acat1;
        if (it == 0)               att_phase<true,  false>(p, Ain);
        else if (it < N_ITERS - 1) att_phase<false, false>(p, Ain);
        else                       att_phase<false, true >(p, Ain);
        grid.sync();
        if (it < N_ITERS - 1) gemm_phase<false>(p, sm, Ain, Aout);
        else                  gemm_phase<true >(p, sm, Ain, nullptr);
        grid.sync();
    }
}

// ---------------- fallback multi-kernel path (if cooperative launch unavailable) -------
__global__ __launch_bounds__(256, 2) void k_prep_f(Pm p) { do_prep(p); }
template <bool FIRST, bool LAST>
__global__ __launch_bounds__(256, 2) void k_att_f(Pm p, bf16* Aout) {
    att_phase<FIRST, LAST>(p, Aout);
}
template <bool LAST>
__global__ __launch_bounds__(256, 2) void k_gemm_f(Pm p, const bf16* Ain, bf16* Aout) {
    __shared__ SMU sm;
    gemm_phase<LAST>(p, sm, Ain, Aout);
}

extern "C" void kernel_launch(void* const* d_in, const int* in_sizes, int n_in,
                              void* d_out, int out_size, void* d_ws, size_t ws_size,
                              hipStream_t stream) {
    char* ws = (char*)d_ws;
    size_t off = 0;
    auto alloc = [&](size_t bytes) -> void* {
        off = (off + 255) & ~(size_t)255;
        void* p = ws + off;
        off += bytes;
        return p;
    };

    Pm p;
    p.xf    = (const float*)d_in[0];
    p.batch = (const int*)d_in[1];
    // d_in[2] = n_graphs scalar (8192, hardcoded)
    p.Wih   = (const float*)d_in[3];
    p.Whh   = (const float*)d_in[4];
    p.bih   = (const float*)d_in[5];
    p.bhh   = (const float*)d_in[6];
    p.n_nodes = in_sizes[0] / DIM;
    p.out   = (float*)d_out;
    p.offs  = (int*)  alloc((size_t)(NG + 1) * sizeof(int));
    p.Wcat  = (bf16*) alloc((size_t)GDIM * KDIM * sizeof(bf16));
    p.bsum  = (float*)alloc((size_t)GDIM * sizeof(float));
    p.Acat0 = (bf16*) alloc((size_t)NG * KDIM * sizeof(bf16));
    p.Acat1 = (bf16*) alloc((size_t)NG * KDIM * sizeof(bf16));
    p.h     = (float*)alloc((size_t)NG * DIM * sizeof(float));
    p.c     = (float*)alloc((size_t)NG * DIM * sizeof(float));
    p.xb    = (unsigned short*)alloc((size_t)p.n_nodes * DIM * sizeof(unsigned short));
    (void)ws_size; (void)n_in; (void)out_size;

    void* args[] = {(void*)&p};
    hipError_t err = hipLaunchCooperativeKernel((void*)k_fused, dim3(GRID_BLOCKS), dim3(256),
                                                args, 0, stream);
    if (err != hipSuccess) {
        // deterministic fallback: same device code, separate launches
        k_prep_f<<<GRID_BLOCKS, 256, 0, stream>>>(p);
        for (int it = 0; it < N_ITERS; ++it) {
            bf16* Ain  = (it & 1) ? p.Acat1 : p.Acat0;
            bf16* Aout = (it & 1) ? p.Acat0 : p.Acat1;
            if (it == 0)
                k_att_f<true,  false><<<GRID_BLOCKS, 256, 0, stream>>>(p, Ain);
            else if (it < N_ITERS - 1)
                k_att_f<false, false><<<GRID_BLOCKS, 256, 0, stream>>>(p, Ain);
            else
                k_att_f<false, true ><<<GRID_BLOCKS, 256, 0, stream>>>(p, Ain);
            if (it < N_ITERS - 1)
                k_gemm_f<false><<<GRID_BLOCKS, 256, 0, stream>>>(p, Ain, Aout);
            else
                k_gemm_f<true ><<<GRID_BLOCKS, 256, 0, stream>>>(p, Ain, nullptr);
        }
    }
}